// Round 8
// baseline (1400.203 us; speedup 1.0000x reference)
//
#include <hip/hip_runtime.h>
#include <math.h>

#define S_   56
#define B_   32
#define C_   1024
#define T_   48
#define TS   47
#define H_   1024
#define EMB_ 512
#define RANK_ 128
#define VOCAB_ 32000
#define G4   4096
#define NBLK 256

// flag-array barrier layout (unsigned words, 128B-strided flags)
#define FL_P    8224
#define FL_SIZE 10496

using bf16x8 = __attribute__((ext_vector_type(8))) __bf16;
using f32x4  = __attribute__((ext_vector_type(4))) float;

__device__ __forceinline__ float sigmoidf_(float x){ return 1.0f/(1.0f+expf(-x)); }
__device__ __forceinline__ float b2f(__bf16 x){ return (float)x; }
__device__ __forceinline__ f32x4 z4(){ f32x4 z = {0.f,0.f,0.f,0.f}; return z; }

// ---------- device-coherent (MALL write-through) store helpers ----------
#define AG __HIP_MEMORY_SCOPE_AGENT
__device__ __forceinline__ void stc_u64(void* p, unsigned long long v){
  __hip_atomic_store((unsigned long long*)p, v, __ATOMIC_RELAXED, AG);
}

// ---------------- shared-memory structures for the persistent kernel ----------------
struct RedShared {
  float red[4][2][16][18];    // [wavepair][mtile][row][col(+pad)]
};
struct AttnShared {
  union { float hS[1024]; float cred[7][64][8]; } u;  // hS dead before cred written
  float sS[64];
  float pS[64];
};
union alignas(16) SharedU { RedShared r; AttnShared a; };

// ---------------- flag-array grid sync primitives (all direct-poll) ----------------
__device__ __forceinline__ void bar_arrive(unsigned* bars, int bi, unsigned e){
  asm volatile("s_waitcnt vmcnt(0)" ::: "memory");
  __syncthreads();
  if (threadIdx.x == 0)
    __hip_atomic_store(bars + (size_t)bi*32, e, __ATOMIC_RELAXED, AG);
}
// direct-poll wait on all 256 arrive flags (every block)
__device__ __forceinline__ void bar_wait(unsigned* bars, unsigned e){
  if (threadIdx.x < 256){
    while (__hip_atomic_load(bars + (size_t)threadIdx.x*32, __ATOMIC_RELAXED, AG) < e)
      __builtin_amdgcn_s_sleep(1);
  }
  __syncthreads();
  asm volatile("" ::: "memory");
}
// direct-poll on the 64 attn producer flags (all blocks)
__device__ __forceinline__ void pflag_wait(unsigned* bars, unsigned t){
  if (threadIdx.x < 64){
    while (__hip_atomic_load(bars + FL_P + (size_t)threadIdx.x*32, __ATOMIC_RELAXED, AG) < t)
      __builtin_amdgcn_s_sleep(1);
  }
  __syncthreads();
  asm volatile("" ::: "memory");
}

// ---------------- prep: enc fp32->bf16 + state init + flag init (one launch) ----------------
// h0bm1: h0[-1] slot (32x1024). fm1: feats[-1] slot (32x2048): h1_init @0, ctx0=0 @1024.
__global__ void k_prep(const float* __restrict__ enc, __bf16* __restrict__ encb,
                       const float* __restrict__ es, __bf16* h0bm1, __bf16* fm1,
                       unsigned* bars){
  int i = blockIdx.x*blockDim.x + threadIdx.x;
  int i4 = i*4;
  if (i4 < S_*32*C_){
    float4 v = *(const float4*)(enc + i4);
    encb[i4+0]=(__bf16)v.x; encb[i4+1]=(__bf16)v.y;
    encb[i4+2]=(__bf16)v.z; encb[i4+3]=(__bf16)v.w;
  }
  if (i < 32*H_){
    int b = i >> 10, j = i & 1023;
    h0bm1[(size_t)b*1024 + j]       = (__bf16)es[i];           // h0 <- es[0]
    fm1[(size_t)b*2048 + j]         = (__bf16)es[32*H_ + i];   // h1 <- es[1]
    fm1[(size_t)b*2048 + 1024 + j]  = (__bf16)0.0f;            // ctx0 = 0
  }
  if (i < FL_SIZE) bars[i] = 0u;
}

// ---------------- fp32 -> bf16 ----------------
__global__ void k_cvt(const float* __restrict__ src, __bf16* __restrict__ dst, int n){
  int i = (blockIdx.x*blockDim.x + threadIdx.x)*4;
  if (i < n){
    float4 v = *(const float4*)(src + i);
    dst[i+0]=(__bf16)v.x; dst[i+1]=(__bf16)v.y; dst[i+2]=(__bf16)v.z; dst[i+3]=(__bf16)v.w;
  }
}

// ---------------- embedding ----------------
__global__ void k_embed(const float* __restrict__ E, const float* __restrict__ P,
                        const int* __restrict__ tok, __bf16* __restrict__ embb){
  int blk = blockIdx.x;            // t*32+b
  int t = blk >> 5, b = blk & 31, tid = threadIdx.x;   // 128 threads
  __shared__ float er[RANK_];
  int tk = tok[b*T_ + t];
  er[tid] = E[(size_t)tk*RANK_ + tid];
  __syncthreads();
  float4 acc = {0.f,0.f,0.f,0.f};
  int e = tid*4;
  for (int r2 = 0; r2 < RANK_; r2++){
    float ev = er[r2];
    float4 p = *(const float4*)(P + (size_t)r2*EMB_ + e);
    acc.x += ev*p.x; acc.y += ev*p.y; acc.z += ev*p.z; acc.w += ev*p.w;
  }
  size_t o = (size_t)blk*EMB_ + e;
  embb[o+0]=(__bf16)acc.x; embb[o+1]=(__bf16)acc.y;
  embb[o+2]=(__bf16)acc.z; embb[o+3]=(__bf16)acc.w;
}

// ---------------- generic B-frag pack (16x16x32) for Wo / P^T ----------------
__global__ void k_packB(const float* __restrict__ src, __bf16* __restrict__ dst,
                        int K, int N, int tr){
  int kk0 = blockIdx.x*32, j0 = blockIdx.y*16, lane = threadIdx.x;  // 64 threads
  int am = lane&15, aq = lane>>4;
  int j = j0 + am;
  __bf16 o8[8];
  #pragma unroll
  for (int i=0;i<8;i++){
    int k = kk0 + aq*8 + i;
    float v = tr ? src[(size_t)j*K + k] : src[(size_t)k*N + j];
    o8[i] = (__bf16)v;
  }
  int NCH = K/32, jt = j0>>4, ch = kk0>>5;
  *(bf16x8*)(dst + (((size_t)jt*NCH + ch)*64 + lane)*8) = *(bf16x8*)o8;
}

// ---------------- chunk accumulate: NC chunks of K=32 against LDS weights ----------------
template<int NC>
__device__ __forceinline__ void accum(f32x4& acc0, f32x4& acc1,
    const __bf16* __restrict__ abase, int rs, const __bf16* wlds,
    int ch0, int am, int aq, int lane)
{
  const __bf16* a0p = abase + (size_t)am*rs + aq*8;
  const __bf16* a1p = abase + (size_t)(am+16)*rs + aq*8;
  const __bf16* wl  = wlds + (size_t)lane*8;
  #pragma unroll
  for (int c=0;c<NC;c++){
    int ch = ch0 + c;
    bf16x8 a0 = *(const bf16x8*)(a0p + (size_t)ch*32);
    bf16x8 a1 = *(const bf16x8*)(a1p + (size_t)ch*32);
    bf16x8 w  = *(const bf16x8*)(wl  + (size_t)ch*512);
    acc0 = __builtin_amdgcn_mfma_f32_16x16x32_bf16(a0, w, acc0, 0, 0, 0);
    acc1 = __builtin_amdgcn_mfma_f32_16x16x32_bf16(a1, w, acc1, 0, 0, 0);
  }
}

// ---------------- 8-wave reduce + LSTM cell (c-state in registers, packed u64 h-store) ----------------
__device__ __forceinline__ void reduce_cell(SharedU& su, const f32x4& acc0, const f32x4& acc1,
    int bi, int tid, const float* __restrict__ bias, float& creg,
    __bf16* __restrict__ hout, int stride)
{
  int kw = tid>>6, lane = tid&63, am = lane&15, aq = lane>>4;
  if (kw >= 4){
    #pragma unroll
    for (int rg=0;rg<4;rg++){
      su.r.red[kw-4][0][aq*4+rg][am] = acc0[rg];
      su.r.red[kw-4][1][aq*4+rg][am] = acc1[rg];
    }
  }
  __syncthreads();
  if (kw < 4){
    #pragma unroll
    for (int rg=0;rg<4;rg++){
      su.r.red[kw][0][aq*4+rg][am] += acc0[rg];
      su.r.red[kw][1][aq*4+rg][am] += acc1[rg];
    }
  }
  __syncthreads();
  if (tid < 128){
    int b = tid>>2, q = tid&3;
    int mt = b>>4, r = b&15;
    float G0=0.f, G1=0.f, G2=0.f, G3=0.f;
    #pragma unroll
    for (int w2=0; w2<4; w2++){
      G0 += su.r.red[w2][mt][r][q];
      G1 += su.r.red[w2][mt][r][4+q];
      G2 += su.r.red[w2][mt][r][8+q];
      G3 += su.r.red[w2][mt][r][12+q];
    }
    int j = bi*4 + q;
    float gi = G0 + bias[j];
    float gf = G1 + bias[1024 + j];
    float gg = G2 + bias[2048 + j];
    float go = G3 + bias[3072 + j];
    float ii = sigmoidf_(gi), ff = sigmoidf_(gf), gv = tanhf(gg), oo = sigmoidf_(go);
    float cv = ff*creg + ii*gv;
    float hv = oo*tanhf(cv);
    creg = cv;
    union { __bf16 h; unsigned short s; } hu; hu.h = (__bf16)hv;
    unsigned h0v = hu.s;
    unsigned h1v = __shfl_down(h0v, 1);
    unsigned h2v = __shfl_down(h0v, 2);
    unsigned h3v = __shfl_down(h0v, 3);
    if (q == 0){
      unsigned long long pk = (unsigned long long)(h0v & 0xffffu)
                            | ((unsigned long long)(h1v & 0xffffu) << 16)
                            | ((unsigned long long)(h2v & 0xffffu) << 32)
                            | ((unsigned long long)(h3v & 0xffffu) << 48);
      stc_u64(hout + (size_t)b*stride + bi*4, pk);
    }
  }
}

// ---------------- attention for one batch row, split PV half (512 threads) ----------------
__device__ __forceinline__ void attn_block(AttnShared& sa, int b, int chalf, int tid,
    const __bf16* __restrict__ encb, const int* __restrict__ enc_lens,
    __bf16* __restrict__ fbt)
{
  if (tid < 128){
    bf16x8 h8 = *(const bf16x8*)(fbt + (size_t)b*2048 + tid*8);
    #pragma unroll
    for (int u=0;u<8;u++) sa.u.hS[tid*8+u] = b2f(h8[u]);
  }
  __syncthreads();
  int w = tid >> 6, lane = tid & 63;
  for (int s = w; s < S_; s += 8){
    const __bf16* er = encb + ((size_t)s*32 + b)*C_;
    float a = 0.f;
    #pragma unroll
    for (int half = 0; half < 2; half++){
      int k = lane*8 + half*512;
      bf16x8 e8 = *(const bf16x8*)(er + k);
      #pragma unroll
      for (int u=0;u<8;u++) a += b2f(e8[u]) * sa.u.hS[k+u];
    }
    #pragma unroll
    for (int off=32; off>0; off>>=1) a += __shfl_down(a, off);
    if (lane == 0) sa.sS[s] = a;
  }
  __syncthreads();
  if (tid < 64){
    int len = enc_lens[b];
    float sc = (tid < len && tid < S_) ? sa.sS[tid] : -1e30f;
    float m = sc;
    #pragma unroll
    for (int off=32; off>0; off>>=1) m = fmaxf(m, __shfl_xor(m, off));
    float e = expf(sc - m);
    float ssum = e;
    #pragma unroll
    for (int off=32; off>0; off>>=1) ssum += __shfl_xor(ssum, off);
    sa.pS[tid] = e / ssum;
  }
  __syncthreads();                    // hS dead past here -> cred may overlay
  int cg = tid & 63, sg = tid >> 6;   // 8-way s-split over this block's 512-col half
  float a8[8];
  #pragma unroll
  for (int i=0;i<8;i++) a8[i] = 0.f;
  for (int s = sg; s < S_; s += 8){
    float p = sa.pS[s];
    bf16x8 e8 = *(const bf16x8*)(encb + ((size_t)s*32 + b)*C_ + chalf*512 + cg*8);
    #pragma unroll
    for (int i=0;i<8;i++) a8[i] += p * b2f(e8[i]);
  }
  if (sg > 0){
    #pragma unroll
    for (int i=0;i<8;i++) sa.u.cred[sg-1][cg][i] = a8[i];
  }
  __syncthreads();
  if (sg == 0){
    union { __bf16 bb[8]; unsigned long long u[2]; } cu;
    #pragma unroll
    for (int i=0;i<8;i++){
      float v = a8[i];
      #pragma unroll
      for (int k=0;k<7;k++) v += sa.u.cred[k][cg][i];
      cu.bb[i] = (__bf16)v;
    }
    stc_u64(fbt + (size_t)b*2048 + 1024 + chalf*512 + cg*8,     cu.u[0]);
    stc_u64(fbt + (size_t)b*2048 + 1024 + chalf*512 + cg*8 + 4, cu.u[1]);
  }
}

// ---------------- persistent decode loop (256 blocks x 512 threads) ----------------
// Weight pack fused into startup: each block reads its 16-col slice of W0/U0/W1/U1
// (float4 = the 4-col q-group) straight into LDS frag order. No WP0/WP1 buffers.
__global__ __launch_bounds__(512) void k_loop(
    const float* __restrict__ W0, const float* __restrict__ U0,
    const float* __restrict__ W1, const float* __restrict__ U1,
    const float* __restrict__ b0, const float* __restrict__ b1,
    __bf16* __restrict__ h0b,      // h0b[t] base (t=0 slot; t=-1 valid below)
    __bf16* __restrict__ featsb,   // featsb[t] base (t=-1 valid below)
    const __bf16* __restrict__ embb,
    const __bf16* __restrict__ encb, const int* __restrict__ enc_lens,
    unsigned* bars)
{
  __shared__ __bf16 wB0[80*512];   // 81920 B : gemm0 weight slice (N=16 gate-cols, K=2560)
  __shared__ __bf16 wB1[64*512];   // 65536 B : gemm1 weight slice (N=16, K=2048)
  __shared__ SharedU su;           // reduce / attention overlay
  int bi = blockIdx.x, tid = threadIdx.x;
  int kw = tid>>6, lane = tid&63, am = lane&15, aq = lane>>4;

  // one-time fused weight pack: fp32 global -> bf16 LDS frag order
  // wB0 K-order: [0,512)=W0 emb rows, [512,1536)=W0 ctx rows, [1536,2560)=U0 rows
  for (int idx = tid; idx < 2560*4; idx += 512){
    int kk = idx >> 2, g = idx & 3;
    const float* src = (kk < 1536) ? (W0 + (size_t)kk*G4) : (U0 + (size_t)(kk-1536)*G4);
    float4 v = *(const float4*)(src + g*1024 + bi*4);
    int ch = kk >> 5, r5 = kk & 31, aq2 = r5 >> 3, i8 = r5 & 7;
    __bf16* d = wB0 + ch*512 + (aq2*16 + g*4)*8 + i8;
    d[0] = (__bf16)v.x; d[8] = (__bf16)v.y; d[16] = (__bf16)v.z; d[24] = (__bf16)v.w;
  }
  // wB1 K-order: [0,1024)=W1 rows, [1024,2048)=U1 rows
  for (int idx = tid; idx < 2048*4; idx += 512){
    int kk = idx >> 2, g = idx & 3;
    const float* src = (kk < 1024) ? (W1 + (size_t)kk*G4) : (U1 + (size_t)(kk-1024)*G4);
    float4 v = *(const float4*)(src + g*1024 + bi*4);
    int ch = kk >> 5, r5 = kk & 31, aq2 = r5 >> 3, i8 = r5 & 7;
    __bf16* d = wB1 + ch*512 + (aq2*16 + g*4)*8 + i8;
    d[0] = (__bf16)v.x; d[8] = (__bf16)v.y; d[16] = (__bf16)v.z; d[24] = (__bf16)v.w;
  }
  __syncthreads();

  float c0r = 0.f, c1r = 0.f;
  f32x4 g00 = z4(), g01 = z4(), g10 = z4(), g11 = z4();

  // prologue: gates0(t=0) partial = emb_0 @ W0e + h0_init @ U0
  accum<2>(g00, g01, embb,                 512,  wB0, kw*2,    am, aq, lane);
  accum<4>(g00, g01, h0b - 32768 - 1536,   1024, wB0, 48+kw*4, am, aq, lane);

  unsigned e = 0;
  for (int t = 0; t < TS; t++){
    const __bf16* fprev = featsb + ((size_t)(t-1))*65536;  // [h1_{t-1}(1024), ctx_t(1024)]
    __bf16* h0t = h0b + (size_t)t*32768;
    __bf16* ft  = featsb + (size_t)t*65536;

    // ---- phase 1: + ctx part -> gates0 -> cell0 -> h0_t ----
    pflag_wait(bars, (unsigned)t);
    accum<4>(g00, g01, fprev + 512, 2048, wB0, 16+kw*4, am, aq, lane);
    reduce_cell(su, g00, g01, bi, tid, b0, c0r, h0t, 1024);
    g00 = z4(); g01 = z4();
    bar_arrive(bars, bi, ++e);
    // spin-work: gates1 partial U1 @ h1_{t-1}
    accum<4>(g10, g11, fprev - 1024, 2048, wB1, 32+kw*4, am, aq, lane);
    bar_wait(bars, e);

    // ---- phase 2: + W1 @ h0_t -> gates1 -> cell1 -> h1_t ----
    accum<4>(g10, g11, h0t, 1024, wB1, kw*4, am, aq, lane);
    reduce_cell(su, g10, g11, bi, tid, b1, c1r, ft, 2048);
    g10 = z4(); g11 = z4();
    bar_arrive(bars, bi, ++e);
    // spin-work: gates0(t+1) partial = emb_{t+1} @ W0 + h0_t @ U0
    if (t + 1 < TS){
      accum<2>(g00, g01, embb + (size_t)(t+1)*16384, 512,  wB0, kw*2,    am, aq, lane);
      accum<4>(g00, g01, h0t - 1536,                 1024, wB0, 48+kw*4, am, aq, lane);
    }

    // ---- phase 3: attention (64 blocks; only they wait for h1) ----
    if (bi < 64){
      bar_wait(bars, e);
      attn_block(su.a, bi & 31, bi >> 5, tid, encb, enc_lens, ft);
      asm volatile("s_waitcnt vmcnt(0)" ::: "memory");
      __syncthreads();
      if (tid == 0)
        __hip_atomic_store(bars + FL_P + (size_t)bi*32, (unsigned)(t+1), __ATOMIC_RELAXED, AG);
    }
  }
}

// ---------------- hproj = tanh(featsb @ WoP + bo) -> hpb (bf16 MFMA) ----------------
__global__ __launch_bounds__(256) void k_hproj_mfma(
    const __bf16* __restrict__ fb, const __bf16* __restrict__ WoP,
    const float* __restrict__ bo, __bf16* __restrict__ hpb)
{
  int nt = blockIdx.x, jb = blockIdx.y, tid = threadIdx.x;  // (47,16)
  int w = tid>>6, lane = tid&63;
  int mt = w&1, jw = w>>1;
  int am = lane&15, aq = lane>>4;
  const __bf16* aRow = fb + ((size_t)(nt*32 + mt*16 + am))*2048 + aq*8;
  int jt = jb*2 + jw;
  const __bf16* bptr = WoP + ((size_t)jt*64)*512 + lane*8;
  f32x4 acc = {0,0,0,0};
  bf16x8 ar0 = *(const bf16x8*)(aRow);
  bf16x8 br0 = *(const bf16x8*)(bptr);
  bf16x8 ar1 = *(const bf16x8*)(aRow + 32);
  bf16x8 br1 = *(const bf16x8*)(bptr + 512);
  for (int ch = 0; ch < 64; ch += 2){
    bf16x8 a0 = ar0, b0 = br0, a1 = ar1, b1 = br1;
    if (ch + 2 < 64){
      ar0 = *(const bf16x8*)(aRow + (ch+2)*32);
      br0 = *(const bf16x8*)(bptr + (size_t)(ch+2)*512);
      ar1 = *(const bf16x8*)(aRow + (ch+3)*32);
      br1 = *(const bf16x8*)(bptr + (size_t)(ch+3)*512);
    }
    acc = __builtin_amdgcn_mfma_f32_16x16x32_bf16(a0, b0, acc, 0, 0, 0);
    acc = __builtin_amdgcn_mfma_f32_16x16x32_bf16(a1, b1, acc, 0, 0, 0);
  }
  int jcol = jb*32 + jw*16 + am;
  float bv = bo[jcol];
  #pragma unroll
  for (int rg=0; rg<4; rg++){
    int m = nt*32 + mt*16 + aq*4 + rg;
    hpb[(size_t)m*512 + jcol] = (__bf16)tanhf(acc[rg] + bv);
  }
}

// ---------------- r = hpb @ P^T -> rbuf (bf16 MFMA) ----------------
__global__ __launch_bounds__(256) void k_rproj_mfma(
    const __bf16* __restrict__ hpb, const __bf16* __restrict__ PP,
    __bf16* __restrict__ rb)
{
  int nt = blockIdx.x, jb = blockIdx.y, tid = threadIdx.x;  // (47,4)
  int w = tid>>6, lane = tid&63;
  int mt = w&1, jw = w>>1;
  int am = lane&15, aq = lane>>4;
  const __bf16* aRow = hpb + ((size_t)(nt*32 + mt*16 + am))*512 + aq*8;
  int jt = jb*2 + jw;
  const __bf16* bptr = PP + ((size_t)jt*16)*512 + lane*8;
  f32x4 acc = {0,0,0,0};
  #pragma unroll
  for (int ch = 0; ch < 16; ch++){
    bf16x8 a = *(const bf16x8*)(aRow + ch*32);
    bf16x8 b = *(const bf16x8*)(bptr + (size_t)ch*512);
    acc = __builtin_amdgcn_mfma_f32_16x16x32_bf16(a, b, acc, 0, 0, 0);
  }
  int jcol = jb*32 + jw*16 + am;
  #pragma unroll
  for (int rg=0; rg<4; rg++){
    int m = nt*32 + mt*16 + aq*4 + rg;
    rb[(size_t)m*RANK_ + jcol] = (__bf16)acc[rg];
  }
}

// ---------------- vocab GEMM: grid 250 v-chunks, loop all 47 n-tiles ----------------
__global__ __launch_bounds__(256) void k_vocab2(
    const __bf16* __restrict__ rb, const __bf16* __restrict__ Eb,
    const int* __restrict__ tok,
    float* __restrict__ mpart, float* __restrict__ lpart,
    float* __restrict__ lablog)
{
  int vc = blockIdx.x, tid = threadIdx.x;
  int w = tid>>6, lane = tid&63;
  int am = lane&15, aq = lane>>4;
  int vb = vc*128 + w*32;
  bf16x8 bfr[2][4];
  #pragma unroll
  for (int vt=0; vt<2; vt++)
    #pragma unroll
    for (int ks=0; ks<4; ks++)
      bfr[vt][ks] = *(const bf16x8*)(Eb + ((size_t)(vb + vt*16 + am))*RANK_ + ks*32 + aq*8);

  __shared__ float redM[4][32], redL[4][32];
  for (int nt = 0; nt < TS; nt++){
    f32x4 acc[2][2] = {{{0,0,0,0},{0,0,0,0}},{{0,0,0,0},{0,0,0,0}}};
    #pragma unroll
    for (int mt=0; mt<2; mt++){
      #pragma unroll
      for (int ks=0; ks<4; ks++){
        bf16x8 a = *(const bf16x8*)(rb + ((size_t)(nt*32 + mt*16 + am))*RANK_ + ks*32 + aq*8);
        acc[mt][0] = __builtin_amdgcn_mfma_f32_16x16x32_bf16(a, bfr[0][ks], acc[mt][0], 0,0,0);
        acc[mt][1] = __builtin_amdgcn_mfma_f32_16x16x32_bf16(a, bfr[1][ks], acc[mt][1], 0,0,0);
      }
    }
    #pragma unroll
    for (int mt=0; mt<2; mt++){
      #pragma unroll
      for (int rg=0; rg<4; rg++){
        int row = mt*16 + aq*4 + rg;
        int n = nt*32 + row;
        int lbl = tok[row*T_ + nt + 1];
        float v0 = acc[mt][0][rg], v1 = acc[mt][1][rg];
        if (vb + am == lbl)      lablog[n] = v0;
        if (vb + 16 + am == lbl) lablog[n] = v1;
        float m = fmaxf(v0, v1);
        #pragma unroll
        for (int off=1; off<16; off<<=1) m = fmaxf(m, __shfl_xor(m, off));
        float l = expf(v0 - m) + expf(v1 - m);
        #pragma unroll
        for (int off=1; off<16; off<<=1) l += __shfl_xor(l, off);
        if (am == 0){ redM[w][row] = m; redL[w][row] = l; }
      }
    }
    __syncthreads();
    if (tid < 32){
      float M = fmaxf(fmaxf(redM[0][tid], redM[1][tid]), fmaxf(redM[2][tid], redM[3][tid]));
      float L = 0.f;
      #pragma unroll
      for (int ww=0; ww<4; ww++) L += redL[ww][tid]*expf(redM[ww][tid] - M);
      mpart[(size_t)(nt*32 + tid)*250 + vc] = M;
      lpart[(size_t)(nt*32 + tid)*250 + vc] = L;
    }
    __syncthreads();
  }
}

// ---------------- loss stage 1 ----------------
__global__ void k_loss1(const float* __restrict__ mpart, const float* __restrict__ lpart,
                        const float* __restrict__ lablog, const int* __restrict__ tgt_lens,
                        float* __restrict__ tpart){
  int t = blockIdx.x, tid = threadIdx.x;
  int row = tid >> 3, cq = tid & 7;
  int n = t*32 + row;
  float m = -1e30f;
  for (int c = cq; c < 250; c += 8) m = fmaxf(m, mpart[(size_t)n*250 + c]);
  #pragma unroll
  for (int off=1; off<8; off<<=1) m = fmaxf(m, __shfl_xor(m, off));
  float l = 0.f;
  for (int c = cq; c < 250; c += 8) l += lpart[(size_t)n*250 + c]*expf(mpart[(size_t)n*250 + c] - m);
  #pragma unroll
  for (int off=1; off<8; off<<=1) l += __shfl_xor(l, off);
  __shared__ float red[32];
  if (cq == 0)
    red[row] = (t < tgt_lens[row] - 1) ? (m + logf(l) - lablog[n]) : 0.f;
  __syncthreads();
  if (tid == 0){
    float s = 0.f;
    #pragma unroll
    for (int i=0;i<32;i++) s += red[i];
    tpart[t] = s;
  }
}

// ---------------- loss stage 2 ----------------
__global__ void k_loss2(const float* __restrict__ tpart, float* __restrict__ out){
  int tid = threadIdx.x;
  float v = (tid < TS) ? tpart[tid] : 0.f;
  #pragma unroll
  for (int off=32; off>0; off>>=1) v += __shfl_down(v, off);
  if (tid == 0) out[0] = v;
}

extern "C" void kernel_launch(void* const* d_in, const int* in_sizes, int n_in,
                              void* d_out, int out_size, void* d_ws, size_t ws_size,
                              hipStream_t stream){
  const float* enc      = (const float*)d_in[0];
  const float* es       = (const float*)d_in[1];
  const int*   tok      = (const int*)  d_in[2];
  const int*   enc_lens = (const int*)  d_in[3];
  const int*   tgt_lens = (const int*)  d_in[4];
  const float* E        = (const float*)d_in[5];
  const float* P        = (const float*)d_in[6];
  const float* W0       = (const float*)d_in[7];
  const float* U0       = (const float*)d_in[8];
  const float* b0       = (const float*)d_in[9];
  const float* W1       = (const float*)d_in[10];
  const float* U1       = (const float*)d_in[11];
  const float* b1       = (const float*)d_in[12];
  const float* Wo       = (const float*)d_in[13];
  const float* bo       = (const float*)d_in[14];
  float* out = (float*)d_out;

  float* fb = (float*)d_ws;
  size_t fo = 0;
  float* mpart = fb + fo; fo += (size_t)TS*32*250;
  float* lpart = fb + fo; fo += (size_t)TS*32*250;
  float* lab   = fb + fo; fo += (size_t)TS*32;
  float* tpart = fb + fo; fo += 64;
  unsigned* bars = (unsigned*)(fb + fo); fo += FL_SIZE;
  __bf16* bb = (__bf16*)(fb + fo);
  size_t bo2 = 0;
  __bf16* encb   = bb + bo2; bo2 += (size_t)S_*32*C_;
  __bf16* embb   = bb + bo2; bo2 += (size_t)TS*32*EMB_;
  __bf16* rbuf   = bb + bo2; bo2 += (size_t)TS*32*RANK_;
  __bf16* WoP    = bb + bo2; bo2 += (size_t)2048*512;
  __bf16* PP     = bb + bo2; bo2 += (size_t)512*128;
  __bf16* featsb0= bb + bo2; bo2 += (size_t)(TS+1)*32*2048;   // slot -1 + 47 steps
  __bf16* hpb    = bb + bo2; bo2 += (size_t)TS*32*EMB_;
  __bf16* h0b0   = bb + bo2; bo2 += (size_t)(TS+1)*32*1024;   // slot -1 + 47 steps
  __bf16* Eb     = bb + bo2; bo2 += (size_t)VOCAB_*RANK_;

  __bf16* featsb = featsb0 + (size_t)32*2048;   // featsb[t], t>=0; [-1] = featsb0
  __bf16* h0b    = h0b0 + (size_t)32*1024;

  k_prep<<<1792, 256, 0, stream>>>(enc, encb, es, h0b0, featsb0, bars);
  k_embed<<<TS*32, 128, 0, stream>>>(E, P, tok, embb);
  k_packB<<<dim3(64,32), 64, 0, stream>>>(Wo, WoP, 2048, 512, 0);
  k_packB<<<dim3(16,8), 64, 0, stream>>>(P, PP, 512, 128, 1);
  k_cvt<<<(VOCAB_*RANK_/4 + 255)/256, 256, 0, stream>>>(E, Eb, VOCAB_*RANK_);

  k_loop<<<NBLK, 512, 0, stream>>>(W0, U0, W1, U1, b0, b1, h0b, featsb,
                                   embb, encb, enc_lens, bars);

  k_hproj_mfma<<<dim3(TS,16), 256, 0, stream>>>(featsb, WoP, bo, hpb);
  k_rproj_mfma<<<dim3(TS,4), 256, 0, stream>>>(hpb, PP, rbuf);
  k_vocab2<<<250, 256, 0, stream>>>(rbuf, Eb, tok, mpart, lpart, lab);
  k_loss1<<<TS, 256, 0, stream>>>(mpart, lpart, lab, tgt_lens, tpart);
  k_loss2<<<1, 64, 0, stream>>>(tpart, out);
}

// Round 9
// 1396.022 us; speedup vs baseline: 1.0030x; 1.0030x over previous
//
#include <hip/hip_runtime.h>
#include <math.h>

#define S_   56
#define B_   32
#define C_   1024
#define T_   48
#define TS   47
#define H_   1024
#define EMB_ 512
#define RANK_ 128
#define VOCAB_ 32000
#define G4   4096
#define NBLK 256

// flag-array barrier layout (unsigned words, 128B-strided flags)
#define FL_DONE 8192
#define FL_P    8224
#define FL_SIZE 10496

using bf16x8 = __attribute__((ext_vector_type(8))) __bf16;
using f32x4  = __attribute__((ext_vector_type(4))) float;

__device__ __forceinline__ float sigmoidf_(float x){ return 1.0f/(1.0f+expf(-x)); }
__device__ __forceinline__ float b2f(__bf16 x){ return (float)x; }
__device__ __forceinline__ f32x4 z4(){ f32x4 z = {0.f,0.f,0.f,0.f}; return z; }

// ---------- device-coherent (MALL write-through) helpers ----------
#define AG __HIP_MEMORY_SCOPE_AGENT
__device__ __forceinline__ void stc_u64(void* p, unsigned long long v){
  __hip_atomic_store((unsigned long long*)p, v, __ATOMIC_RELAXED, AG);
}
__device__ __forceinline__ void stc_f32(float* p, float v){
  __hip_atomic_store(p, v, __ATOMIC_RELAXED, AG);
}
__device__ __forceinline__ float ldc_f32(const float* p){
  return __hip_atomic_load(p, __ATOMIC_RELAXED, AG);
}

// ---------------- shared-memory structures for the persistent kernel ----------------
struct RedShared {
  float red[4][2][16][18];
};
struct AttnShared {
  union { float hS[1024]; float cred[7][64][8]; } u;
  float sS[64];
  float pS[64];
};
struct VocShared {
  float redM[4][32];
  float redL[4][32];
  float red1[32];
};
union alignas(16) SharedU { RedShared r; AttnShared a; VocShared v; };

// ---------------- flag-array grid sync primitives (round-7 proven) ----------------
__device__ __forceinline__ void bar_arrive(unsigned* bars, int bi, unsigned e){
  asm volatile("s_waitcnt vmcnt(0)" ::: "memory");
  __syncthreads();
  if (threadIdx.x == 0)
    __hip_atomic_store(bars + (size_t)bi*32, e, __ATOMIC_RELAXED, AG);
}
// full barrier, observer = block 255 publishes FL_DONE, others poll it
__device__ __forceinline__ void bar_wait_all(unsigned* bars, int bi, unsigned e){
  if (bi == 255){
    if (threadIdx.x < 256){
      while (__hip_atomic_load(bars + (size_t)threadIdx.x*32, __ATOMIC_RELAXED, AG) < e) {}
    }
    __syncthreads();
    if (threadIdx.x == 0)
      __hip_atomic_store(bars + FL_DONE, e, __ATOMIC_RELAXED, AG);
  } else {
    if (threadIdx.x == 0){
      while (__hip_atomic_load(bars + FL_DONE, __ATOMIC_RELAXED, AG) < e) {}
    }
    __syncthreads();
  }
  asm volatile("" ::: "memory");
}
// direct-poll wait on all 256 arrive flags (used by the 64 attn blocks)
__device__ __forceinline__ void bar_wait_direct(unsigned* bars, unsigned e){
  if (threadIdx.x < 256){
    while (__hip_atomic_load(bars + (size_t)threadIdx.x*32, __ATOMIC_RELAXED, AG) < e) {}
  }
  __syncthreads();
  asm volatile("" ::: "memory");
}
// direct-poll on the 64 attn producer flags (all blocks)
__device__ __forceinline__ void pflag_wait(unsigned* bars, unsigned t){
  if (threadIdx.x < 64){
    while (__hip_atomic_load(bars + FL_P + (size_t)threadIdx.x*32, __ATOMIC_RELAXED, AG) < t)
      __builtin_amdgcn_s_sleep(1);
  }
  __syncthreads();
  asm volatile("" ::: "memory");
}

// ================= k_pre: ALL pre-loop work in one launch =================
// block id ranges:
//  [0,1280)    pack2 W0/U0 -> WP0   (ch=id%80, gy=id/80)
//  [1280,2304) pack2 W1/U1 -> WP1   (ch=p%64, gy=p/64)
//  [2304,2816) packB Wo -> WoP      (4 sub-units of 64 thr per block)
//  [2816,2848) packB P^T -> PP
//  [2848,4352) embed (tid<128 active)
//  [4352,6400) grid-stride scalars: enc cvt, E cvt, state init, flag init
__global__ __launch_bounds__(256) void k_pre(
    const float* __restrict__ W0, const float* __restrict__ U0,
    const float* __restrict__ W1, const float* __restrict__ U1,
    const float* __restrict__ Wo, const float* __restrict__ P,
    const float* __restrict__ E,  const float* __restrict__ enc,
    const float* __restrict__ es, const int* __restrict__ tok,
    __bf16* __restrict__ WP0, __bf16* __restrict__ WP1,
    __bf16* __restrict__ WoP, __bf16* __restrict__ PP,
    __bf16* __restrict__ Eb,  __bf16* __restrict__ encb,
    __bf16* __restrict__ embb, __bf16* __restrict__ h0bm1,
    __bf16* __restrict__ fm1, unsigned* __restrict__ bars)
{
  __shared__ union { __bf16 Tl[32][264]; float er[RANK_]; } sp;
  int id = blockIdx.x, tid = threadIdx.x;

  if (id < 2304){
    // ---- pack2: [W;U] -> per-block LDS-resident frag order ----
    const float* A; const float* Bs; __bf16* dst; int K1, NCH, p;
    if (id < 1280){ p = id;        A = W0; Bs = U0; dst = WP0; K1 = 1536; NCH = 80; }
    else          { p = id - 1280; A = W1; Bs = U1; dst = WP1; K1 = 1024; NCH = 64; }
    int ch = (NCH==80) ? (p % 80) : (p % 64);
    int gy = (NCH==80) ? (p / 80) : (p / 64);
    int g = gy >> 2, band = gy & 3;
    {
      int r = tid>>3, cs = tid&7;
      int kk = ch*32 + r;
      const float* src = (kk < K1) ? (A + (size_t)kk*G4 + g*1024 + band*256 + cs*32)
                                   : (Bs + (size_t)(kk-K1)*G4 + g*1024 + band*256 + cs*32);
      #pragma unroll
      for (int u=0;u<8;u++){
        float4 v = *(const float4*)(src + u*4);
        sp.Tl[r][cs*32+u*4+0]=(__bf16)v.x; sp.Tl[r][cs*32+u*4+1]=(__bf16)v.y;
        sp.Tl[r][cs*32+u*4+2]=(__bf16)v.z; sp.Tl[r][cs*32+u*4+3]=(__bf16)v.w;
      }
    }
    __syncthreads();
    int bil = tid>>2, aq = tid&3;
    int bi = band*64 + bil;
    #pragma unroll
    for (int q=0;q<4;q++){
      __bf16 o8[8];
      #pragma unroll
      for (int i=0;i<8;i++) o8[i] = sp.Tl[aq*8+i][bil*4+q];
      int lane = aq*16 + g*4 + q;
      *(bf16x8*)(dst + (((size_t)bi*NCH + ch)*64 + lane)*8) = *(bf16x8*)o8;
    }
  } else if (id < 2848){
    // ---- packB: Wo (tr=0) and P^T (tr=1) ----
    int sub = tid>>6, lane = tid&63;
    int am = lane&15, aq = lane>>4;
    const float* src; __bf16* dst; int K, N, tr, unit;
    if (id < 2816){ unit = (id-2304)*4 + sub; src = Wo; dst = WoP; K = 2048; N = 512; tr = 0; }
    else          { unit = (id-2816)*4 + sub; src = P;  dst = PP;  K = 512;  N = 128; tr = 1; }
    int nbx = K/32;
    int bx = unit % nbx, by = unit / nbx;
    int kk0 = bx*32, j0 = by*16;
    int j = j0 + am;
    __bf16 o8[8];
    #pragma unroll
    for (int i=0;i<8;i++){
      int k = kk0 + aq*8 + i;
      float v = tr ? src[(size_t)j*K + k] : src[(size_t)k*N + j];
      o8[i] = (__bf16)v;
    }
    int NCH = K/32, jt = j0>>4, ch = kk0>>5;
    *(bf16x8*)(dst + (((size_t)jt*NCH + ch)*64 + lane)*8) = *(bf16x8*)o8;
  } else if (id < 4352){
    // ---- embed ----
    int blk = id - 2848;           // t*32+b
    int t = blk >> 5, b = blk & 31;
    int tk = tok[b*T_ + t];
    if (tid < 128) sp.er[tid] = E[(size_t)tk*RANK_ + tid];
    __syncthreads();
    if (tid < 128){
      float4 acc = {0.f,0.f,0.f,0.f};
      int e = tid*4;
      for (int r2 = 0; r2 < RANK_; r2++){
        float ev = sp.er[r2];
        float4 p = *(const float4*)(P + (size_t)r2*EMB_ + e);
        acc.x += ev*p.x; acc.y += ev*p.y; acc.z += ev*p.z; acc.w += ev*p.w;
      }
      size_t o = (size_t)blk*EMB_ + e;
      embb[o+0]=(__bf16)acc.x; embb[o+1]=(__bf16)acc.y;
      embb[o+2]=(__bf16)acc.z; embb[o+3]=(__bf16)acc.w;
    }
  } else {
    // ---- grid-stride scalar region ----
    const unsigned NE = 458752u;            // enc float4 units
    const unsigned NEB = 1024000u;          // E float4 units
    const unsigned NI = 32768u;             // init units
    const unsigned NF = FL_SIZE;            // flag units
    unsigned u0 = (unsigned)(id - 4352)*256u + (unsigned)tid;
    for (unsigned u = u0; u < NE+NEB+NI+NF; u += 2048u*256u){
      if (u < NE){
        int i4 = u*4;
        float4 v = *(const float4*)(enc + i4);
        encb[i4+0]=(__bf16)v.x; encb[i4+1]=(__bf16)v.y;
        encb[i4+2]=(__bf16)v.z; encb[i4+3]=(__bf16)v.w;
      } else if (u < NE+NEB){
        int i4 = (u-NE)*4;
        float4 v = *(const float4*)(E + i4);
        Eb[i4+0]=(__bf16)v.x; Eb[i4+1]=(__bf16)v.y;
        Eb[i4+2]=(__bf16)v.z; Eb[i4+3]=(__bf16)v.w;
      } else if (u < NE+NEB+NI){
        unsigned i = u - NE - NEB;
        int b = i >> 10, j = i & 1023;
        h0bm1[(size_t)b*1024 + j]       = (__bf16)es[i];
        fm1[(size_t)b*2048 + j]         = (__bf16)es[32*H_ + i];
        fm1[(size_t)b*2048 + 1024 + j]  = (__bf16)0.0f;
      } else {
        bars[u - NE - NEB - NI] = 0u;
      }
    }
  }
}

// ---------------- chunk accumulate: NC chunks of K=32 against LDS weights ----------------
template<int NC>
__device__ __forceinline__ void accum(f32x4& acc0, f32x4& acc1,
    const __bf16* __restrict__ abase, int rs, const __bf16* wlds,
    int ch0, int am, int aq, int lane)
{
  const __bf16* a0p = abase + (size_t)am*rs + aq*8;
  const __bf16* a1p = abase + (size_t)(am+16)*rs + aq*8;
  const __bf16* wl  = wlds + (size_t)lane*8;
  #pragma unroll
  for (int c=0;c<NC;c++){
    int ch = ch0 + c;
    bf16x8 a0 = *(const bf16x8*)(a0p + (size_t)ch*32);
    bf16x8 a1 = *(const bf16x8*)(a1p + (size_t)ch*32);
    bf16x8 w  = *(const bf16x8*)(wl  + (size_t)ch*512);
    acc0 = __builtin_amdgcn_mfma_f32_16x16x32_bf16(a0, w, acc0, 0, 0, 0);
    acc1 = __builtin_amdgcn_mfma_f32_16x16x32_bf16(a1, w, acc1, 0, 0, 0);
  }
}

// ---------------- 8-wave reduce + LSTM cell (c-state in regs, packed u64 h-store) ----------------
__device__ __forceinline__ void reduce_cell(SharedU& su, const f32x4& acc0, const f32x4& acc1,
    int bi, int tid, const float* __restrict__ bias, float& creg,
    __bf16* __restrict__ hout, int stride)
{
  int kw = tid>>6, lane = tid&63, am = lane&15, aq = lane>>4;
  if (kw >= 4){
    #pragma unroll
    for (int rg=0;rg<4;rg++){
      su.r.red[kw-4][0][aq*4+rg][am] = acc0[rg];
      su.r.red[kw-4][1][aq*4+rg][am] = acc1[rg];
    }
  }
  __syncthreads();
  if (kw < 4){
    #pragma unroll
    for (int rg=0;rg<4;rg++){
      su.r.red[kw][0][aq*4+rg][am] += acc0[rg];
      su.r.red[kw][1][aq*4+rg][am] += acc1[rg];
    }
  }
  __syncthreads();
  if (tid < 128){
    int b = tid>>2, q = tid&3;
    int mt = b>>4, r = b&15;
    float G0=0.f, G1=0.f, G2=0.f, G3=0.f;
    #pragma unroll
    for (int w2=0; w2<4; w2++){
      G0 += su.r.red[w2][mt][r][q];
      G1 += su.r.red[w2][mt][r][4+q];
      G2 += su.r.red[w2][mt][r][8+q];
      G3 += su.r.red[w2][mt][r][12+q];
    }
    int j = bi*4 + q;
    float gi = G0 + bias[j];
    float gf = G1 + bias[1024 + j];
    float gg = G2 + bias[2048 + j];
    float go = G3 + bias[3072 + j];
    float ii = sigmoidf_(gi), ff = sigmoidf_(gf), gv = tanhf(gg), oo = sigmoidf_(go);
    float cv = ff*creg + ii*gv;
    float hv = oo*tanhf(cv);
    creg = cv;
    union { __bf16 h; unsigned short s; } hu; hu.h = (__bf16)hv;
    unsigned h0v = hu.s;
    unsigned h1v = __shfl_down(h0v, 1);
    unsigned h2v = __shfl_down(h0v, 2);
    unsigned h3v = __shfl_down(h0v, 3);
    if (q == 0){
      unsigned long long pk = (unsigned long long)(h0v & 0xffffu)
                            | ((unsigned long long)(h1v & 0xffffu) << 16)
                            | ((unsigned long long)(h2v & 0xffffu) << 32)
                            | ((unsigned long long)(h3v & 0xffffu) << 48);
      stc_u64(hout + (size_t)b*stride + bi*4, pk);
    }
  }
}

// ---------------- attention for one batch row, split PV half (512 threads) ----------------
__device__ __forceinline__ void attn_block(AttnShared& sa, int b, int chalf, int tid,
    const __bf16* __restrict__ encb, const int* __restrict__ enc_lens,
    __bf16* __restrict__ fbt)
{
  if (tid < 128){
    bf16x8 h8 = *(const bf16x8*)(fbt + (size_t)b*2048 + tid*8);
    #pragma unroll
    for (int u=0;u<8;u++) sa.u.hS[tid*8+u] = b2f(h8[u]);
  }
  __syncthreads();
  int w = tid >> 6, lane = tid & 63;
  for (int s = w; s < S_; s += 8){
    const __bf16* er = encb + ((size_t)s*32 + b)*C_;
    float a = 0.f;
    #pragma unroll
    for (int half = 0; half < 2; half++){
      int k = lane*8 + half*512;
      bf16x8 e8 = *(const bf16x8*)(er + k);
      #pragma unroll
      for (int u=0;u<8;u++) a += b2f(e8[u]) * sa.u.hS[k+u];
    }
    #pragma unroll
    for (int off=32; off>0; off>>=1) a += __shfl_down(a, off);
    if (lane == 0) sa.sS[s] = a;
  }
  __syncthreads();
  if (tid < 64){
    int len = enc_lens[b];
    float sc = (tid < len && tid < S_) ? sa.sS[tid] : -1e30f;
    float m = sc;
    #pragma unroll
    for (int off=32; off>0; off>>=1) m = fmaxf(m, __shfl_xor(m, off));
    float e = expf(sc - m);
    float ssum = e;
    #pragma unroll
    for (int off=32; off>0; off>>=1) ssum += __shfl_xor(ssum, off);
    sa.pS[tid] = e / ssum;
  }
  __syncthreads();
  int cg = tid & 63, sg = tid >> 6;
  float a8[8];
  #pragma unroll
  for (int i=0;i<8;i++) a8[i] = 0.f;
  for (int s = sg; s < S_; s += 8){
    float p = sa.pS[s];
    bf16x8 e8 = *(const bf16x8*)(encb + ((size_t)s*32 + b)*C_ + chalf*512 + cg*8);
    #pragma unroll
    for (int i=0;i<8;i++) a8[i] += p * b2f(e8[i]);
  }
  if (sg > 0){
    #pragma unroll
    for (int i=0;i<8;i++) sa.u.cred[sg-1][cg][i] = a8[i];
  }
  __syncthreads();
  if (sg == 0){
    union { __bf16 bb[8]; unsigned long long u[2]; } cu;
    #pragma unroll
    for (int i=0;i<8;i++){
      float v = a8[i];
      #pragma unroll
      for (int k=0;k<7;k++) v += sa.u.cred[k][cg][i];
      cu.bb[i] = (__bf16)v;
    }
    stc_u64(fbt + (size_t)b*2048 + 1024 + chalf*512 + cg*8,     cu.u[0]);
    stc_u64(fbt + (size_t)b*2048 + 1024 + chalf*512 + cg*8 + 4, cu.u[1]);
  }
}

// ---------------- fused tail stage bodies ----------------
__device__ __forceinline__ void hproj_tile(int nt, int jq, int tid,
    const __bf16* __restrict__ fb, const __bf16* __restrict__ WoP,
    const float* __restrict__ bo, __bf16* __restrict__ hpb)
{
  int w = tid>>6, lane = tid&63;
  int mt = w&1, jw = w>>1;                  // jw 0..3
  int am = lane&15, aq = lane>>4;
  int jt = jq*4 + jw;                       // 0..31
  const __bf16* aRow = fb + ((size_t)(nt*32 + mt*16 + am))*2048 + aq*8;
  const __bf16* bptr = WoP + ((size_t)jt*64)*512 + lane*8;
  f32x4 acc = {0,0,0,0};
  for (int ch = 0; ch < 64; ch++){
    bf16x8 a = *(const bf16x8*)(aRow + ch*32);
    bf16x8 b = *(const bf16x8*)(bptr + (size_t)ch*512);
    acc = __builtin_amdgcn_mfma_f32_16x16x32_bf16(a, b, acc, 0, 0, 0);
  }
  int jcol = jt*16 + am;
  float bv = bo[jcol];
  #pragma unroll
  for (int rg=0; rg<4; rg++){
    int m = nt*32 + mt*16 + aq*4 + rg;
    union { __bf16 h; unsigned short s; } hu; hu.h = (__bf16)tanhf(acc[rg] + bv);
    unsigned v0 = hu.s;
    unsigned v1 = __shfl_down(v0,1);
    unsigned v2 = __shfl_down(v0,2);
    unsigned v3 = __shfl_down(v0,3);
    if ((am&3)==0){
      unsigned long long pk = (unsigned long long)(v0&0xffffu)
        | ((unsigned long long)(v1&0xffffu)<<16)
        | ((unsigned long long)(v2&0xffffu)<<32)
        | ((unsigned long long)(v3&0xffffu)<<48);
      stc_u64(hpb + (size_t)m*512 + jcol, pk);
    }
  }
}

__device__ __forceinline__ void rproj_tile(int nt, int half, int tid,
    const __bf16* __restrict__ hpb, const __bf16* __restrict__ PP,
    __bf16* __restrict__ rb)
{
  int w = tid>>6, lane = tid&63;
  int jb = half*2 + (w>>2);                 // 0..3
  int mt = w&1, jw = (w>>1)&1;
  int am = lane&15, aq = lane>>4;
  int jt = jb*2 + jw;                       // 0..7
  const __bf16* aRow = hpb + ((size_t)(nt*32 + mt*16 + am))*512 + aq*8;
  const __bf16* bptr = PP + ((size_t)jt*16)*512 + lane*8;
  f32x4 acc = {0,0,0,0};
  #pragma unroll
  for (int ch = 0; ch < 16; ch++){
    bf16x8 a = *(const bf16x8*)(aRow + ch*32);
    bf16x8 b = *(const bf16x8*)(bptr + (size_t)ch*512);
    acc = __builtin_amdgcn_mfma_f32_16x16x32_bf16(a, b, acc, 0, 0, 0);
  }
  int jcol = jt*16 + am;
  #pragma unroll
  for (int rg=0; rg<4; rg++){
    int m = nt*32 + mt*16 + aq*4 + rg;
    union { __bf16 h; unsigned short s; } hu; hu.h = (__bf16)acc[rg];
    unsigned v0 = hu.s;
    unsigned v1 = __shfl_down(v0,1);
    unsigned v2 = __shfl_down(v0,2);
    unsigned v3 = __shfl_down(v0,3);
    if ((am&3)==0){
      unsigned long long pk = (unsigned long long)(v0&0xffffu)
        | ((unsigned long long)(v1&0xffffu)<<16)
        | ((unsigned long long)(v2&0xffffu)<<32)
        | ((unsigned long long)(v3&0xffffu)<<48);
      stc_u64(rb + (size_t)m*RANK_ + jcol, pk);
    }
  }
}

__device__ __forceinline__ void vocab_chunk(SharedU& su, int vc, int tid,
    const __bf16* __restrict__ rb, const __bf16* __restrict__ Eb,
    const int* __restrict__ tok,
    float* __restrict__ mpart, float* __restrict__ lpart,
    float* __restrict__ lablog)
{
  int w = tid>>6, lane = tid&63;
  int am = lane&15, aq = lane>>4;
  int vb = vc*128 + w*32;
  bf16x8 bfr[2][4];
  if (tid < 256){
    #pragma unroll
    for (int vt=0; vt<2; vt++)
      #pragma unroll
      for (int ks=0; ks<4; ks++)
        bfr[vt][ks] = *(const bf16x8*)(Eb + ((size_t)(vb + vt*16 + am))*RANK_ + ks*32 + aq*8);
  }
  for (int nt = 0; nt < TS; nt++){
    if (tid < 256){
      f32x4 acc[2][2] = {{{0,0,0,0},{0,0,0,0}},{{0,0,0,0},{0,0,0,0}}};
      #pragma unroll
      for (int mt=0; mt<2; mt++){
        #pragma unroll
        for (int ks=0; ks<4; ks++){
          bf16x8 a = *(const bf16x8*)(rb + ((size_t)(nt*32 + mt*16 + am))*RANK_ + ks*32 + aq*8);
          acc[mt][0] = __builtin_amdgcn_mfma_f32_16x16x32_bf16(a, bfr[0][ks], acc[mt][0], 0,0,0);
          acc[mt][1] = __builtin_amdgcn_mfma_f32_16x16x32_bf16(a, bfr[1][ks], acc[mt][1], 0,0,0);
        }
      }
      #pragma unroll
      for (int mt=0; mt<2; mt++){
        #pragma unroll
        for (int rg=0; rg<4; rg++){
          int row = mt*16 + aq*4 + rg;
          int n = nt*32 + row;
          int lbl = tok[row*T_ + nt + 1];
          float v0 = acc[mt][0][rg], v1 = acc[mt][1][rg];
          if (vb + am == lbl)      stc_f32(lablog + n, v0);
          if (vb + 16 + am == lbl) stc_f32(lablog + n, v1);
          float m = fmaxf(v0, v1);
          #pragma unroll
          for (int off=1; off<16; off<<=1) m = fmaxf(m, __shfl_xor(m, off));
          float l = expf(v0 - m) + expf(v1 - m);
          #pragma unroll
          for (int off=1; off<16; off<<=1) l += __shfl_xor(l, off);
          if (am == 0){ su.v.redM[w][row] = m; su.v.redL[w][row] = l; }
        }
      }
    }
    __syncthreads();
    if (tid < 32){
      float M = fmaxf(fmaxf(su.v.redM[0][tid], su.v.redM[1][tid]),
                      fmaxf(su.v.redM[2][tid], su.v.redM[3][tid]));
      float L = 0.f;
      #pragma unroll
      for (int ww=0; ww<4; ww++) L += su.v.redL[ww][tid]*expf(su.v.redM[ww][tid] - M);
      stc_f32(mpart + (size_t)(nt*32 + tid)*250 + vc, M);
      stc_f32(lpart + (size_t)(nt*32 + tid)*250 + vc, L);
    }
    __syncthreads();
  }
}

__device__ __forceinline__ void loss1_block(SharedU& su, int t, int tid,
    const float* __restrict__ mpart, const float* __restrict__ lpart,
    const float* __restrict__ lablog, const int* __restrict__ tgt_lens,
    float* __restrict__ tpart)
{
  if (tid < 256){
    int row = tid >> 3, cq = tid & 7;
    int n = t*32 + row;
    float m = -1e30f;
    for (int c = cq; c < 250; c += 8) m = fmaxf(m, ldc_f32(mpart + (size_t)n*250 + c));
    #pragma unroll
    for (int off=1; off<8; off<<=1) m = fmaxf(m, __shfl_xor(m, off));
    float l = 0.f;
    for (int c = cq; c < 250; c += 8)
      l += ldc_f32(lpart + (size_t)n*250 + c)*expf(ldc_f32(mpart + (size_t)n*250 + c) - m);
    #pragma unroll
    for (int off=1; off<8; off<<=1) l += __shfl_xor(l, off);
    if (cq == 0)
      su.v.red1[row] = (t < tgt_lens[row] - 1) ? (m + logf(l) - ldc_f32(lablog + n)) : 0.f;
  }
  __syncthreads();
  if (tid == 0){
    float s = 0.f;
    #pragma unroll
    for (int i=0;i<32;i++) s += su.v.red1[i];
    stc_f32(tpart + t, s);
  }
}

// ---------------- persistent kernel: decode loop + fused tail ----------------
__global__ __launch_bounds__(512) void k_loop(
    const __bf16* __restrict__ WP0, const __bf16* __restrict__ WP1,
    const float* __restrict__ b0, const float* __restrict__ b1,
    __bf16* __restrict__ h0b, __bf16* __restrict__ featsb,
    const __bf16* __restrict__ embb,
    const __bf16* __restrict__ encb, const int* __restrict__ enc_lens,
    unsigned* bars,
    const __bf16* __restrict__ WoP, const float* __restrict__ bo,
    const __bf16* __restrict__ PP, const __bf16* __restrict__ Eb,
    const int* __restrict__ tok, const int* __restrict__ tgt_lens,
    __bf16* __restrict__ hpb, __bf16* __restrict__ rbuf,
    float* __restrict__ mpart, float* __restrict__ lpart,
    float* __restrict__ lab, float* __restrict__ tpart,
    float* __restrict__ out)
{
  __shared__ __bf16 wB0[80*512];
  __shared__ __bf16 wB1[64*512];
  __shared__ SharedU su;
  int bi = blockIdx.x, tid = threadIdx.x;
  int kw = tid>>6, lane = tid&63, am = lane&15, aq = lane>>4;

  // one-time weight load into LDS (coalesced from pre-packed WP)
  {
    const bf16x8* g0 = (const bf16x8*)(WP0 + (size_t)bi*80*512);
    const bf16x8* g1 = (const bf16x8*)(WP1 + (size_t)bi*64*512);
    bf16x8* l0 = (bf16x8*)wB0;
    bf16x8* l1 = (bf16x8*)wB1;
    for (int idx = tid; idx < 80*64; idx += 512) l0[idx] = g0[idx];
    for (int idx = tid; idx < 64*64; idx += 512) l1[idx] = g1[idx];
  }
  __syncthreads();

  float c0r = 0.f, c1r = 0.f;
  f32x4 g00 = z4(), g01 = z4(), g10 = z4(), g11 = z4();

  // prologue: gates0(t=0) partial = emb_0 @ W0e + h0_init @ U0
  accum<2>(g00, g01, embb,                 512,  wB0, kw*2,    am, aq, lane);
  accum<4>(g00, g01, h0b - 32768 - 1536,   1024, wB0, 48+kw*4, am, aq, lane);

  unsigned e = 0;
  for (int t = 0; t < TS; t++){
    const __bf16* fprev = featsb + ((size_t)(t-1))*65536;
    __bf16* h0t = h0b + (size_t)t*32768;
    __bf16* ft  = featsb + (size_t)t*65536;

    // ---- phase 1: + ctx part -> gates0 -> cell0 -> h0_t ----
    pflag_wait(bars, (unsigned)t);
    accum<4>(g00, g01, fprev + 512, 2048, wB0, 16+kw*4, am, aq, lane);
    reduce_cell(su, g00, g01, bi, tid, b0, c0r, h0t, 1024);
    g00 = z4(); g01 = z4();
    bar_arrive(bars, bi, ++e);
    accum<4>(g10, g11, fprev - 1024, 2048, wB1, 32+kw*4, am, aq, lane);
    bar_wait_all(bars, bi, e);

    // ---- phase 2: + W1 @ h0_t -> gates1 -> cell1 -> h1_t ----
    accum<4>(g10, g11, h0t, 1024, wB1, kw*4, am, aq, lane);
    reduce_cell(su, g10, g11, bi, tid, b1, c1r, ft, 2048);
    g10 = z4(); g11 = z4();
    bar_arrive(bars, bi, ++e);
    if (t + 1 < TS){
      accum<2>(g00, g01, embb + (size_t)(t+1)*16384, 512,  wB0, kw*2,    am, aq, lane);
      accum<4>(g00, g01, h0t - 1536,                 1024, wB0, 48+kw*4, am, aq, lane);
    }

    // ---- phase 3: attention (64 blocks; only they wait for h1) ----
    if (bi < 64){
      bar_wait_direct(bars, e);
      attn_block(su.a, bi & 31, bi >> 5, tid, encb, enc_lens, ft);
      asm volatile("s_waitcnt vmcnt(0)" ::: "memory");
      __syncthreads();
      if (tid == 0)
        __hip_atomic_store(bars + FL_P + (size_t)bi*32, (unsigned)(t+1), __ATOMIC_RELAXED, AG);
    }
  }

  // ================= fused tail =================
  pflag_wait(bars, (unsigned)TS);         // all ctx_46 writes visible

  // stage 1: hproj (376 tiles)
  for (int tau = bi; tau < 376; tau += 256)
    hproj_tile(tau >> 3, tau & 7, tid, featsb, WoP, bo, hpb);
  bar_arrive(bars, bi, ++e);
  bar_wait_all(bars, bi, e);

  // stage 2: rproj (94 tiles)
  if (bi < 94)
    rproj_tile(bi >> 1, bi & 1, tid, hpb, PP, rbuf);
  bar_arrive(bars, bi, ++e);
  bar_wait_all(bars, bi, e);

  // stage 3: vocab (250 chunks)
  if (bi < 250)
    vocab_chunk(su, bi, tid, rbuf, Eb, tok, mpart, lpart, lab);
  bar_arrive(bars, bi, ++e);
  bar_wait_all(bars, bi, e);

  // stage 4: loss1 (47 rows)
  if (bi < 47)
    loss1_block(su, bi, tid, mpart, lpart, lab, tgt_lens, tpart);
  bar_arrive(bars, bi, ++e);
  bar_wait_all(bars, bi, e);

  // stage 5: loss2 (block 0)
  if (bi == 0 && tid < 64){
    float v = (tid < TS) ? ldc_f32(tpart + tid) : 0.f;
    #pragma unroll
    for (int off=32; off>0; off>>=1) v += __shfl_down(v, off);
    if (tid == 0) out[0] = v;
  }
}

extern "C" void kernel_launch(void* const* d_in, const int* in_sizes, int n_in,
                              void* d_out, int out_size, void* d_ws, size_t ws_size,
                              hipStream_t stream){
  const float* enc      = (const float*)d_in[0];
  const float* es       = (const float*)d_in[1];
  const int*   tok      = (const int*)  d_in[2];
  const int*   enc_lens = (const int*)  d_in[3];
  const int*   tgt_lens = (const int*)  d_in[4];
  const float* E        = (const float*)d_in[5];
  const float* P        = (const float*)d_in[6];
  const float* W0       = (const float*)d_in[7];
  const float* U0       = (const float*)d_in[8];
  const float* b0       = (const float*)d_in[9];
  const float* W1       = (const float*)d_in[10];
  const float* U1       = (const float*)d_in[11];
  const float* b1       = (const float*)d_in[12];
  const float* Wo       = (const float*)d_in[13];
  const float* bo       = (const float*)d_in[14];
  float* out = (float*)d_out;

  float* fb = (float*)d_ws;
  size_t fo = 0;
  unsigned* bars = (unsigned*)(fb + fo); fo += FL_SIZE;
  __bf16* bb = (__bf16*)(fb + fo);
  size_t bo2 = 0;
  __bf16* WP0    = bb + bo2; bo2 += (size_t)256*80*512;
  __bf16* WP1    = bb + bo2; bo2 += (size_t)256*64*512;
  __bf16* encb   = bb + bo2; bo2 += (size_t)S_*32*C_;
  __bf16* embb   = bb + bo2; bo2 += (size_t)TS*32*EMB_;
  __bf16* rbuf   = bb + bo2; bo2 += (size_t)TS*32*RANK_;
  __bf16* WoP    = bb + bo2; bo2 += (size_t)2048*512;
  __bf16* PP     = bb + bo2; bo2 += (size_t)512*128;
  __bf16* featsb0= bb + bo2; bo2 += (size_t)(TS+1)*32*2048;
  __bf16* hpb    = bb + bo2; bo2 += (size_t)TS*32*EMB_;
  __bf16* h0b0   = bb + bo2; bo2 += (size_t)(TS+1)*32*1024;
  __bf16* Eb     = bb + bo2; bo2 += (size_t)VOCAB_*RANK_;

  __bf16* featsb = featsb0 + (size_t)32*2048;   // featsb[t], t>=0; [-1] = featsb0
  __bf16* h0b    = h0b0 + (size_t)32*1024;

  // mpart/lpart/lab/tpart alias featsb0 (dead after hproj stage); consumers use agent loads
  float* mpart = (float*)featsb0;
  float* lpart = mpart + (size_t)TS*32*250;
  float* lab   = lpart + (size_t)TS*32*250;
  float* tpart = lab + (size_t)TS*32;

  k_pre<<<6400, 256, 0, stream>>>(W0, U0, W1, U1, Wo, P, E, enc, es, tok,
                                  WP0, WP1, WoP, PP, Eb, encb, embb,
                                  h0b0, featsb0, bars);

  k_loop<<<NBLK, 512, 0, stream>>>(WP0, WP1, b0, b1, h0b, featsb,
                                   embb, encb, enc_lens, bars,
                                   WoP, bo, PP, Eb, tok, tgt_lens,
                                   hpb, rbuf, mpart, lpart, lab, tpart, out);
}